// Round 12
// baseline (165.960 us; speedup 1.0000x reference)
//
#include <hip/hip_runtime.h>
#include <stdint.h>

typedef unsigned short u16;
typedef __attribute__((ext_vector_type(4))) float floatx4;
typedef __attribute__((ext_vector_type(8))) __bf16 bf16x8;

__device__ __forceinline__ u16 f2bf(float f) {
  uint32_t u = __float_as_uint(f);
  u += 0x7FFFu + ((u >> 16) & 1u);
  return (u16)(u >> 16);
}

// ---------------- fused prep: cast x (blocks 0..6143) + W transpose (6144..6719) ----------------
__global__ __launch_bounds__(256) void prep_fused_kernel(
    const float* __restrict__ x, u16* __restrict__ xb,
    const float* __restrict__ Wq, const float* __restrict__ Wk,
    const float* __restrict__ Wv, const float* __restrict__ Wo,
    const float* __restrict__ bq, const float* __restrict__ bk, const float* __restrict__ bv,
    u16* __restrict__ Wt, u16* __restrict__ Wto, float* __restrict__ bias) {
  __shared__ u16 sT[64][72];
  const int bx = blockIdx.x;
  const int tid = threadIdx.x;
  if (bx < 6144) {                       // ---- cast path ----
    int i = bx * 256 + tid;
    const float4* p = (const float4*)x;
    float4 a = p[(size_t)i * 2];
    float4 b = p[(size_t)i * 2 + 1];
    uint32_t w0 = (uint32_t)f2bf(a.x) | ((uint32_t)f2bf(a.y) << 16);
    uint32_t w1 = (uint32_t)f2bf(a.z) | ((uint32_t)f2bf(a.w) << 16);
    uint32_t w2 = (uint32_t)f2bf(b.x) | ((uint32_t)f2bf(b.y) << 16);
    uint32_t w3 = (uint32_t)f2bf(b.z) | ((uint32_t)f2bf(b.w) << 16);
    *(uint4*)(xb + (size_t)i * 8) = make_uint4(w0, w1, w2, w3);
    return;
  }
  // ---- prep path ----
  const int pid = bx - 6144;             // 0..575
  const int mat = pid / 144;
  const int rem = pid - mat * 144;
  const int ktb = rem % 12, ntb = rem / 12;
  const int kt = ktb * 64, nt = ntb * 64;
  const float* W = mat == 0 ? Wq : mat == 1 ? Wk : mat == 2 ? Wv : Wo;
  const int r = tid >> 2, c4 = tid & 3;
#pragma unroll
  for (int p = 0; p < 4; ++p) {
    int c = c4 * 16 + p * 4;
    float4 v = *(const float4*)&W[(size_t)(kt + r) * 768 + nt + c];
    sT[c + 0][r] = f2bf(v.x);
    sT[c + 1][r] = f2bf(v.y);
    sT[c + 2][r] = f2bf(v.z);
    sT[c + 3][r] = f2bf(v.w);
  }
  __syncthreads();
  const int n = tid >> 2, kq = tid & 3;
  uint4 o0 = *(const uint4*)&sT[n][kq * 16];
  uint4 o1 = *(const uint4*)&sT[n][kq * 16 + 8];
  u16* dst = (mat < 3 ? Wt + ((size_t)(mat * 768 + nt + n)) * 768
                      : Wto + (size_t)(nt + n) * 768) + kt + kq * 16;
  *(uint4*)dst = o0;
  *(uint4*)(dst + 8) = o1;
  if (mat < 3 && ktb == 0 && tid < 64) {
    const float* bs = mat == 0 ? bq : mat == 1 ? bk : bv;
    bias[mat * 768 + nt + tid] = bs[nt + tid];
  }
}

__device__ __forceinline__ void gload16(const void* g, void* l) {
  __builtin_amdgcn_global_load_lds((const __attribute__((address_space(1))) void*)g,
                                   (__attribute__((address_space(3))) void*)l,
                                   16, 0, 0);
}

// ---------------- GEMM: 128x128, BK=64, XOR-swizzled LDS (R7 structure) ----------------
template <int OUTF32>
__global__ __launch_bounds__(256, 4) void gemm_bt_kernel(
    const u16* __restrict__ A, const u16* __restrict__ Bt,
    const float* __restrict__ bias, void* __restrict__ Cv, int ldc) {
  __shared__ __align__(16) u16 Alds[128 * 64];
  __shared__ __align__(16) u16 Blds[128 * 64];
  const int m0 = blockIdx.x * 128, n0 = blockIdx.y * 128;
  const int tid = threadIdx.x;
  const int lane = tid & 63, wid = tid >> 6;
  const int wr = wid >> 1, wc = wid & 1;
  const int l15 = lane & 15, l4 = lane >> 4;
  const int srow = lane >> 3;
  const int csw = (lane & 7) ^ srow;

  floatx4 zz = {0.f, 0.f, 0.f, 0.f};
  floatx4 acc[4][4];
#pragma unroll
  for (int i = 0; i < 4; ++i)
#pragma unroll
    for (int j = 0; j < 4; ++j) acc[i][j] = zz;

  for (int kt = 0; kt < 768; kt += 64) {
#pragma unroll
    for (int i = 0; i < 4; ++i) {
      int u = wid * 4 + i;
      int row = u * 8 + srow;
      gload16(A + (size_t)(m0 + row) * 768 + kt + csw * 8, (char*)Alds + u * 1024);
      gload16(Bt + (size_t)(n0 + row) * 768 + kt + csw * 8, (char*)Blds + u * 1024);
    }
    __syncthreads();
#pragma unroll
    for (int kk = 0; kk < 2; ++kk) {
      bf16x8 af[4], bfr[4];
#pragma unroll
      for (int i = 0; i < 4; ++i) {
        int ra = wr * 64 + i * 16 + l15;
        int rb = wc * 64 + i * 16 + l15;
        af[i]  = *(const bf16x8*)((char*)Alds + ra * 128 + (((kk * 4 + l4) ^ (l15 & 7)) << 4));
        bfr[i] = *(const bf16x8*)((char*)Blds + rb * 128 + (((kk * 4 + l4) ^ (l15 & 7)) << 4));
      }
#pragma unroll
      for (int i = 0; i < 4; ++i)
#pragma unroll
        for (int j = 0; j < 4; ++j)
          acc[i][j] = __builtin_amdgcn_mfma_f32_16x16x32_bf16(af[i], bfr[j], acc[i][j], 0, 0, 0);
    }
    __syncthreads();
  }

#pragma unroll
  for (int i = 0; i < 4; ++i) {
    int row = m0 + wr * 64 + i * 16 + l4 * 4;
#pragma unroll
    for (int j = 0; j < 4; ++j) {
      int col = n0 + wc * 64 + j * 16 + l15;
      float bv = bias[col];
#pragma unroll
      for (int r = 0; r < 4; ++r) {
        float v = acc[i][j][r] + bv;
        if (OUTF32) ((float*)Cv)[(size_t)(row + r) * ldc + col] = v;
        else        ((u16*)Cv)[(size_t)(row + r) * ldc + col] = f2bf(v);
      }
    }
  }
}

// ---------------- fused attention: structure-A, 32KB LDS (mask from global) ----------------
// Single K buf staged at transition, exactly 32KB LDS -> aim 3 blocks/CU.
__global__ __launch_bounds__(512, 4) void attn_kernel(const u16* __restrict__ qkv,
                                                      const float* __restrict__ mask,
                                                      u16* __restrict__ ctx) {
  __shared__ __align__(16) char lds[32768];
  char* sK = lds;                      // [128 s][64 d] bf16, 16B-chunk ^= (s&7)
  char* sV = lds + 16384;              // [64 d][128 s] bf16 (V^T), swizzled

  const int bid = blockIdx.x;
  const int wg = (bid & 7) * 192 + (bid >> 3);   // XCD swizzle (1536 = 8*192)
  const int qt = wg & 3;
  const int h = (wg >> 2) % 12;
  const int b = wg / 48;

  const int tid = threadIdx.x;
  const int lane = tid & 63, w = tid >> 6;
  const int l15 = lane & 15, l4 = lane >> 4;
  const int hi = lane >> 3, doct = lane & 7;

  const u16* base = qkv + (size_t)b * 512 * 2304 + h * 64;
  const u16* Qg = base;
  const u16* Kg = base + 768;
  const u16* Vg = base + 1536;
  const float* mrow = mask + (size_t)b * 512;

  const int csw = doct ^ hi;
  const int vp_ = w * 8 + hi;      // s-pair index 0..63 within a 128-row tile

  auto stageK = [&](int t) {   // 2 gload_lds per wave; pre-swizzled source
    const u16* src = Kg + (size_t)(t * 128 + w * 16) * 2304;
#pragma unroll
    for (int i = 0; i < 2; ++i)
      gload16(src + (size_t)(i * 8 + hi) * 2304 + csw * 8,
              sK + (w * 2 + i) * 1024);
  };
  uint4 vra, vrb;
  auto loadV = [&](int t) {    // 2 global 16B loads -> regs (T14 issue-early)
    const u16* vp = Vg + (size_t)(t * 128 + vp_ * 2) * 2304 + doct * 8;
    vra = *(const uint4*)vp;
    vrb = *(const uint4*)(vp + 2304);
  };
  auto writeV = [&]() {        // regs -> sV transposed, conflict-free swizzle
    const u16* pa = (const u16*)&vra;
    const u16* pb = (const u16*)&vrb;
#pragma unroll
    for (int j = 0; j < 8; ++j) {
      int d = doct * 8 + j;
      uint32_t val = (uint32_t)pa[j] | ((uint32_t)pb[j] << 16);
      *(uint32_t*)(sV + d * 256 +
                   ((4 * vp_) ^ ((d & 7) << 4) ^ (((d >> 3) & 3) << 5))) = val;
    }
  };

  // ---- prologue: everything for tile 0 ----
  stageK(0);
  loadV(0);
  const u16* qp = Qg + (size_t)(qt * 128 + w * 16 + l15) * 2304 + l4 * 8;
  bf16x8 qf0 = *(const bf16x8*)qp;
  bf16x8 qf1 = *(const bf16x8*)(qp + 32);
  writeV();
  asm volatile("s_waitcnt vmcnt(0) lgkmcnt(0)" ::: "memory");
  __builtin_amdgcn_sched_barrier(0);
  __builtin_amdgcn_s_barrier();

  floatx4 zz = {0.f, 0.f, 0.f, 0.f};
  floatx4 oacc[4];
#pragma unroll
  for (int da = 0; da < 4; ++da) oacc[da] = zz;
  float m_ = -1e30f, l_ = 0.f;

  const int kswz = (l15 & 7) << 4;
  const int src0 = l15 + 32 * (l4 & 1);
  const int src1 = src0 + 16;
  const bool csel = (l4 & 2) != 0;

  for (int t = 0; t < 4; ++t) {
    if (t < 3) loadV(t + 1);     // T14: issue next V loads under this phase

    // ---- QK^T (swapped): sacc[ct] rows = k, cols = q ----
    floatx4 sacc[8];
#pragma unroll
    for (int ct = 0; ct < 8; ++ct) sacc[ct] = zz;
    __builtin_amdgcn_s_setprio(1);
#pragma unroll
    for (int ct = 0; ct < 8; ++ct) {
      const char* kr = sK + (ct * 16 + l15) * 128;
      bf16x8 k0 = *(const bf16x8*)(kr + ((16 * l4) ^ kswz));
      bf16x8 k1 = *(const bf16x8*)(kr + ((64 + 16 * l4) ^ kswz));
      sacc[ct] = __builtin_amdgcn_mfma_f32_16x16x32_bf16(k0, qf0, sacc[ct], 0, 0, 0);
      sacc[ct] = __builtin_amdgcn_mfma_f32_16x16x32_bf16(k1, qf1, sacc[ct], 0, 0, 0);
    }
    __builtin_amdgcn_s_setprio(0);

    // ---- online softmax: per-lane over 32 k-values, 2 shfl_xor over l4 group ----
    float pm = -1e30f;
#pragma unroll
    for (int ct = 0; ct < 8; ++ct) {
      floatx4 mv = *(const floatx4*)(mrow + t * 128 + ct * 16 + l4 * 4);
#pragma unroll
      for (int j = 0; j < 4; ++j) {
        float v = sacc[ct][j] * 0.125f + mv[j];
        sacc[ct][j] = v;
        pm = fmaxf(pm, v);
      }
    }
    pm = fmaxf(pm, __shfl_xor(pm, 16, 64));
    pm = fmaxf(pm, __shfl_xor(pm, 32, 64));
    if (__any(pm > m_ + 8.f)) {   // T13 defer-max: rescale only on real growth
      float nm = fmaxf(m_, pm);
      float sc = __expf(m_ - nm);
      m_ = nm;
      l_ *= sc;
#pragma unroll
      for (int da = 0; da < 4; ++da)
#pragma unroll
        for (int j = 0; j < 4; ++j) oacc[da][j] *= sc;
    }
    float ts = 0.f;
#pragma unroll
    for (int ct = 0; ct < 8; ++ct)
#pragma unroll
      for (int j = 0; j < 4; ++j) {
        float e = __expf(sacc[ct][j] - m_);
        sacc[ct][j] = e;
        ts += e;
      }
    ts += __shfl_xor(ts, 16, 64);
    ts += __shfl_xor(ts, 32, 64);
    l_ += ts;

    // ---- pack P to bf16 pairs (consecutive k per word) ----
    uint32_t pk[8][2];
#pragma unroll
    for (int ct = 0; ct < 8; ++ct) {
#pragma unroll
      for (int p = 0; p < 2; ++p) {
        uint32_t ua = __float_as_uint(sacc[ct][2 * p]) + 0x8000u;
        uint32_t ub = __float_as_uint(sacc[ct][2 * p + 1]) + 0x8000u;
        pk[ct][p] = (ua >> 16) | (ub & 0xFFFF0000u);
      }
    }

    // ---- PV: O^T += V^T * P^T; pf gathered via shuffles ----
    __builtin_amdgcn_s_setprio(1);
#pragma unroll
    for (int ks = 0; ks < 4; ++ks) {
      uint32_t A0 = __shfl((int)pk[2 * ks][0], src0, 64);
      uint32_t B0 = __shfl((int)pk[2 * ks + 1][0], src0, 64);
      uint32_t A1 = __shfl((int)pk[2 * ks][1], src0, 64);
      uint32_t B1 = __shfl((int)pk[2 * ks + 1][1], src0, 64);
      uint32_t A2 = __shfl((int)pk[2 * ks][0], src1, 64);
      uint32_t B2 = __shfl((int)pk[2 * ks + 1][0], src1, 64);
      uint32_t A3 = __shfl((int)pk[2 * ks][1], src1, 64);
      uint32_t B3 = __shfl((int)pk[2 * ks + 1][1], src1, 64);
      union { uint32_t u[4]; bf16x8 v; } pf;
      pf.u[0] = csel ? B0 : A0;
      pf.u[1] = csel ? B1 : A1;
      pf.u[2] = csel ? B2 : A2;
      pf.u[3] = csel ? B3 : A3;
#pragma unroll
      for (int da = 0; da < 4; ++da) {
        int dd = da * 16 + l15;
        bf16x8 vf = *(const bf16x8*)(sV + dd * 256 +
            ((64 * ks + 16 * l4) ^ ((dd & 7) << 4) ^ (((dd >> 3) & 3) << 5)));
        oacc[da] = __builtin_amdgcn_mfma_f32_16x16x32_bf16(vf, pf.v, oacc[da], 0, 0, 0);
      }
    }
    __builtin_amdgcn_s_setprio(0);

    // ---- transition: restage K and V for t+1 ----
    asm volatile("s_waitcnt lgkmcnt(0)" ::: "memory");
    __builtin_amdgcn_sched_barrier(0);
    __builtin_amdgcn_s_barrier();        // all reads of sK/sV done
    if (t < 3) {
      stageK(t + 1);
      writeV();
      asm volatile("s_waitcnt vmcnt(0) lgkmcnt(0)" ::: "memory");
      __builtin_amdgcn_sched_barrier(0);
      __builtin_amdgcn_s_barrier();      // new tiles published
    }
  }

  // ---- epilogue: O[q][d] = oacc^T / l ----
  float rl = 1.0f / l_;
  u16* op = ctx + ((size_t)b * 512 + qt * 128 + w * 16 + l15) * 768 + h * 64;
#pragma unroll
  for (int da = 0; da < 4; ++da) {
    ushort4 o;
    o.x = f2bf(oacc[da][0] * rl);
    o.y = f2bf(oacc[da][1] * rl);
    o.z = f2bf(oacc[da][2] * rl);
    o.w = f2bf(oacc[da][3] * rl);
    *(ushort4*)(op + da * 16 + l4 * 4) = o;
  }
}

// ---------------- launch ----------------
extern "C" void kernel_launch(void* const* d_in, const int* in_sizes, int n_in,
                              void* d_out, int out_size, void* d_ws, size_t ws_size,
                              hipStream_t stream) {
  const float* x    = (const float*)d_in[0];
  const float* mask = (const float*)d_in[1];
  const float* Wq   = (const float*)d_in[2];
  const float* bq   = (const float*)d_in[3];
  const float* Wk   = (const float*)d_in[4];
  const float* bk   = (const float*)d_in[5];
  const float* Wv   = (const float*)d_in[6];
  const float* bv   = (const float*)d_in[7];
  const float* Wo   = (const float*)d_in[8];
  const float* bo   = (const float*)d_in[9];
  float* out = (float*)d_out;

  char* ws = (char*)d_ws;
  u16*   xb   = (u16*)ws;                          // 16384*768   bf16
  u16*   ctx  = (u16*)(ws + 25165824);             // 16384*768   bf16
  u16*   qkv  = (u16*)(ws + 50331648);             // 16384*2304  bf16
  u16*   wtq  = (u16*)(ws + 125829120);            // 2304*768    bf16
  u16*   wto  = (u16*)(ws + 129368064);            // 768*768     bf16
  float* bqkv = (float*)(ws + 130547712);          // 2304        f32

  prep_fused_kernel<<<6720, 256, 0, stream>>>(x, xb, Wq, Wk, Wv, Wo, bq, bk, bv,
                                              wtq, wto, bqkv);
  gemm_bt_kernel<0><<<dim3(128, 18), 256, 0, stream>>>(xb, wtq, bqkv, (void*)qkv, 2304);
  attn_kernel<<<dim3(1536), dim3(512), 0, stream>>>(qkv, mask, ctx);
  gemm_bt_kernel<1><<<dim3(128, 6), 256, 0, stream>>>(ctx, wto, bo, (void*)out, 768);
}

// Round 13
// 160.579 us; speedup vs baseline: 1.0335x; 1.0335x over previous
//
#include <hip/hip_runtime.h>
#include <stdint.h>

typedef unsigned short u16;
typedef __attribute__((ext_vector_type(4))) float floatx4;
typedef __attribute__((ext_vector_type(8))) __bf16 bf16x8;

__device__ __forceinline__ u16 f2bf(float f) {
  uint32_t u = __float_as_uint(f);
  u += 0x7FFFu + ((u >> 16) & 1u);
  return (u16)(u >> 16);
}

// ---------------- fused prep: cast x (blocks 0..6143) + W transpose (6144..6719) ----------------
__global__ __launch_bounds__(256) void prep_fused_kernel(
    const float* __restrict__ x, u16* __restrict__ xb,
    const float* __restrict__ Wq, const float* __restrict__ Wk,
    const float* __restrict__ Wv, const float* __restrict__ Wo,
    const float* __restrict__ bq, const float* __restrict__ bk, const float* __restrict__ bv,
    u16* __restrict__ Wt, u16* __restrict__ Wto, float* __restrict__ bias) {
  __shared__ u16 sT[64][72];
  const int bx = blockIdx.x;
  const int tid = threadIdx.x;
  if (bx < 6144) {                       // ---- cast path ----
    int i = bx * 256 + tid;
    const float4* p = (const float4*)x;
    float4 a = p[(size_t)i * 2];
    float4 b = p[(size_t)i * 2 + 1];
    uint32_t w0 = (uint32_t)f2bf(a.x) | ((uint32_t)f2bf(a.y) << 16);
    uint32_t w1 = (uint32_t)f2bf(a.z) | ((uint32_t)f2bf(a.w) << 16);
    uint32_t w2 = (uint32_t)f2bf(b.x) | ((uint32_t)f2bf(b.y) << 16);
    uint32_t w3 = (uint32_t)f2bf(b.z) | ((uint32_t)f2bf(b.w) << 16);
    *(uint4*)(xb + (size_t)i * 8) = make_uint4(w0, w1, w2, w3);
    return;
  }
  // ---- prep path ----
  const int pid = bx - 6144;             // 0..575
  const int mat = pid / 144;
  const int rem = pid - mat * 144;
  const int ktb = rem % 12, ntb = rem / 12;
  const int kt = ktb * 64, nt = ntb * 64;
  const float* W = mat == 0 ? Wq : mat == 1 ? Wk : mat == 2 ? Wv : Wo;
  const int r = tid >> 2, c4 = tid & 3;
#pragma unroll
  for (int p = 0; p < 4; ++p) {
    int c = c4 * 16 + p * 4;
    float4 v = *(const float4*)&W[(size_t)(kt + r) * 768 + nt + c];
    sT[c + 0][r] = f2bf(v.x);
    sT[c + 1][r] = f2bf(v.y);
    sT[c + 2][r] = f2bf(v.z);
    sT[c + 3][r] = f2bf(v.w);
  }
  __syncthreads();
  const int n = tid >> 2, kq = tid & 3;
  uint4 o0 = *(const uint4*)&sT[n][kq * 16];
  uint4 o1 = *(const uint4*)&sT[n][kq * 16 + 8];
  u16* dst = (mat < 3 ? Wt + ((size_t)(mat * 768 + nt + n)) * 768
                      : Wto + (size_t)(nt + n) * 768) + kt + kq * 16;
  *(uint4*)dst = o0;
  *(uint4*)(dst + 8) = o1;
  if (mat < 3 && ktb == 0 && tid < 64) {
    const float* bs = mat == 0 ? bq : mat == 1 ? bk : bv;
    bias[mat * 768 + nt + tid] = bs[nt + tid];
  }
}

__device__ __forceinline__ void gload16(const void* g, void* l) {
  __builtin_amdgcn_global_load_lds((const __attribute__((address_space(1))) void*)g,
                                   (__attribute__((address_space(3))) void*)l,
                                   16, 0, 0);
}

// ---------------- GEMM: 128x128, BK=64, XOR-swizzled LDS (R7 structure) ----------------
template <int OUTF32>
__global__ __launch_bounds__(256, 4) void gemm_bt_kernel(
    const u16* __restrict__ A, const u16* __restrict__ Bt,
    const float* __restrict__ bias, void* __restrict__ Cv, int ldc) {
  __shared__ __align__(16) u16 Alds[128 * 64];
  __shared__ __align__(16) u16 Blds[128 * 64];
  const int m0 = blockIdx.x * 128, n0 = blockIdx.y * 128;
  const int tid = threadIdx.x;
  const int lane = tid & 63, wid = tid >> 6;
  const int wr = wid >> 1, wc = wid & 1;
  const int l15 = lane & 15, l4 = lane >> 4;
  const int srow = lane >> 3;
  const int csw = (lane & 7) ^ srow;

  floatx4 zz = {0.f, 0.f, 0.f, 0.f};
  floatx4 acc[4][4];
#pragma unroll
  for (int i = 0; i < 4; ++i)
#pragma unroll
    for (int j = 0; j < 4; ++j) acc[i][j] = zz;

  for (int kt = 0; kt < 768; kt += 64) {
#pragma unroll
    for (int i = 0; i < 4; ++i) {
      int u = wid * 4 + i;
      int row = u * 8 + srow;
      gload16(A + (size_t)(m0 + row) * 768 + kt + csw * 8, (char*)Alds + u * 1024);
      gload16(Bt + (size_t)(n0 + row) * 768 + kt + csw * 8, (char*)Blds + u * 1024);
    }
    __syncthreads();
#pragma unroll
    for (int kk = 0; kk < 2; ++kk) {
      bf16x8 af[4], bfr[4];
#pragma unroll
      for (int i = 0; i < 4; ++i) {
        int ra = wr * 64 + i * 16 + l15;
        int rb = wc * 64 + i * 16 + l15;
        af[i]  = *(const bf16x8*)((char*)Alds + ra * 128 + (((kk * 4 + l4) ^ (l15 & 7)) << 4));
        bfr[i] = *(const bf16x8*)((char*)Blds + rb * 128 + (((kk * 4 + l4) ^ (l15 & 7)) << 4));
      }
#pragma unroll
      for (int i = 0; i < 4; ++i)
#pragma unroll
        for (int j = 0; j < 4; ++j)
          acc[i][j] = __builtin_amdgcn_mfma_f32_16x16x32_bf16(af[i], bfr[j], acc[i][j], 0, 0, 0);
    }
    __syncthreads();
  }

#pragma unroll
  for (int i = 0; i < 4; ++i) {
    int row = m0 + wr * 64 + i * 16 + l4 * 4;
#pragma unroll
    for (int j = 0; j < 4; ++j) {
      int col = n0 + wc * 64 + j * 16 + l15;
      float bv = bias[col];
#pragma unroll
      for (int r = 0; r < 4; ++r) {
        float v = acc[i][j][r] + bv;
        if (OUTF32) ((float*)Cv)[(size_t)(row + r) * ldc + col] = v;
        else        ((u16*)Cv)[(size_t)(row + r) * ldc + col] = f2bf(v);
      }
    }
  }
}

// ---------------- fused attention: structure-A (R11-exact) ----------------
// Single K buf staged at transition, 34.8KB LDS (sM in LDS), T13 defer-max, T5 setprio.
__global__ __launch_bounds__(512, 4) void attn_kernel(const u16* __restrict__ qkv,
                                                      const float* __restrict__ mask,
                                                      u16* __restrict__ ctx) {
  __shared__ __align__(16) char lds[34816];
  char* sK = lds;                      // [128 s][64 d] bf16, 16B-chunk ^= (s&7)
  char* sV = lds + 16384;              // [64 d][128 s] bf16 (V^T), swizzled
  float* sM = (float*)(lds + 32768);   // mask, 512 f32 linear

  const int bid = blockIdx.x;
  const int wg = (bid & 7) * 192 + (bid >> 3);   // XCD swizzle (1536 = 8*192)
  const int qt = wg & 3;
  const int h = (wg >> 2) % 12;
  const int b = wg / 48;

  const int tid = threadIdx.x;
  const int lane = tid & 63, w = tid >> 6;
  const int l15 = lane & 15, l4 = lane >> 4;
  const int hi = lane >> 3, doct = lane & 7;

  const u16* base = qkv + (size_t)b * 512 * 2304 + h * 64;
  const u16* Qg = base;
  const u16* Kg = base + 768;
  const u16* Vg = base + 1536;

  const int csw = doct ^ hi;
  const int vp_ = w * 8 + hi;      // s-pair index 0..63 within a 128-row tile

  auto stageK = [&](int t) {   // 2 gload_lds per wave; pre-swizzled source
    const u16* src = Kg + (size_t)(t * 128 + w * 16) * 2304;
#pragma unroll
    for (int i = 0; i < 2; ++i)
      gload16(src + (size_t)(i * 8 + hi) * 2304 + csw * 8,
              sK + (w * 2 + i) * 1024);
  };
  uint4 vra, vrb;
  auto loadV = [&](int t) {    // 2 global 16B loads -> regs (T14 issue-early)
    const u16* vp = Vg + (size_t)(t * 128 + vp_ * 2) * 2304 + doct * 8;
    vra = *(const uint4*)vp;
    vrb = *(const uint4*)(vp + 2304);
  };
  auto writeV = [&]() {        // regs -> sV transposed, conflict-free swizzle
    const u16* pa = (const u16*)&vra;
    const u16* pb = (const u16*)&vrb;
#pragma unroll
    for (int j = 0; j < 8; ++j) {
      int d = doct * 8 + j;
      uint32_t val = (uint32_t)pa[j] | ((uint32_t)pb[j] << 16);
      *(uint32_t*)(sV + d * 256 +
                   ((4 * vp_) ^ ((d & 7) << 4) ^ (((d >> 3) & 3) << 5))) = val;
    }
  };

  // ---- prologue: everything for tile 0 ----
  float mval = mask[(size_t)b * 512 + tid];
  stageK(0);
  loadV(0);
  const u16* qp = Qg + (size_t)(qt * 128 + w * 16 + l15) * 2304 + l4 * 8;
  bf16x8 qf0 = *(const bf16x8*)qp;
  bf16x8 qf1 = *(const bf16x8*)(qp + 32);
  sM[tid] = mval;
  writeV();
  asm volatile("s_waitcnt vmcnt(0) lgkmcnt(0)" ::: "memory");
  __builtin_amdgcn_sched_barrier(0);
  __builtin_amdgcn_s_barrier();

  floatx4 zz = {0.f, 0.f, 0.f, 0.f};
  floatx4 oacc[4];
#pragma unroll
  for (int da = 0; da < 4; ++da) oacc[da] = zz;
  float m_ = -1e30f, l_ = 0.f;

  const int kswz = (l15 & 7) << 4;
  const int src0 = l15 + 32 * (l4 & 1);
  const int src1 = src0 + 16;
  const bool csel = (l4 & 2) != 0;

  for (int t = 0; t < 4; ++t) {
    if (t < 3) loadV(t + 1);     // T14: issue next V loads under this phase

    // ---- QK^T (swapped): sacc[ct] rows = k, cols = q ----
    floatx4 sacc[8];
#pragma unroll
    for (int ct = 0; ct < 8; ++ct) sacc[ct] = zz;
    __builtin_amdgcn_s_setprio(1);
#pragma unroll
    for (int ct = 0; ct < 8; ++ct) {
      const char* kr = sK + (ct * 16 + l15) * 128;
      bf16x8 k0 = *(const bf16x8*)(kr + ((16 * l4) ^ kswz));
      bf16x8 k1 = *(const bf16x8*)(kr + ((64 + 16 * l4) ^ kswz));
      sacc[ct] = __builtin_amdgcn_mfma_f32_16x16x32_bf16(k0, qf0, sacc[ct], 0, 0, 0);
      sacc[ct] = __builtin_amdgcn_mfma_f32_16x16x32_bf16(k1, qf1, sacc[ct], 0, 0, 0);
    }
    __builtin_amdgcn_s_setprio(0);

    // ---- online softmax: per-lane over 32 k-values, 2 shfl_xor over l4 group ----
    float pm = -1e30f;
#pragma unroll
    for (int ct = 0; ct < 8; ++ct) {
      floatx4 mv = *(const floatx4*)(sM + t * 128 + ct * 16 + l4 * 4);
#pragma unroll
      for (int j = 0; j < 4; ++j) {
        float v = sacc[ct][j] * 0.125f + mv[j];
        sacc[ct][j] = v;
        pm = fmaxf(pm, v);
      }
    }
    pm = fmaxf(pm, __shfl_xor(pm, 16, 64));
    pm = fmaxf(pm, __shfl_xor(pm, 32, 64));
    if (__any(pm > m_ + 8.f)) {   // T13 defer-max: rescale only on real growth
      float nm = fmaxf(m_, pm);
      float sc = __expf(m_ - nm);
      m_ = nm;
      l_ *= sc;
#pragma unroll
      for (int da = 0; da < 4; ++da)
#pragma unroll
        for (int j = 0; j < 4; ++j) oacc[da][j] *= sc;
    }
    float ts = 0.f;
#pragma unroll
    for (int ct = 0; ct < 8; ++ct)
#pragma unroll
      for (int j = 0; j < 4; ++j) {
        float e = __expf(sacc[ct][j] - m_);
        sacc[ct][j] = e;
        ts += e;
      }
    ts += __shfl_xor(ts, 16, 64);
    ts += __shfl_xor(ts, 32, 64);
    l_ += ts;

    // ---- pack P to bf16 pairs (consecutive k per word) ----
    uint32_t pk[8][2];
#pragma unroll
    for (int ct = 0; ct < 8; ++ct) {
#pragma unroll
      for (int p = 0; p < 2; ++p) {
        uint32_t ua = __float_as_uint(sacc[ct][2 * p]) + 0x8000u;
        uint32_t ub = __float_as_uint(sacc[ct][2 * p + 1]) + 0x8000u;
        pk[ct][p] = (ua >> 16) | (ub & 0xFFFF0000u);
      }
    }

    // ---- PV: O^T += V^T * P^T; pf gathered via shuffles ----
    __builtin_amdgcn_s_setprio(1);
#pragma unroll
    for (int ks = 0; ks < 4; ++ks) {
      uint32_t A0 = __shfl((int)pk[2 * ks][0], src0, 64);
      uint32_t B0 = __shfl((int)pk[2 * ks + 1][0], src0, 64);
      uint32_t A1 = __shfl((int)pk[2 * ks][1], src0, 64);
      uint32_t B1 = __shfl((int)pk[2 * ks + 1][1], src0, 64);
      uint32_t A2 = __shfl((int)pk[2 * ks][0], src1, 64);
      uint32_t B2 = __shfl((int)pk[2 * ks + 1][0], src1, 64);
      uint32_t A3 = __shfl((int)pk[2 * ks][1], src1, 64);
      uint32_t B3 = __shfl((int)pk[2 * ks + 1][1], src1, 64);
      union { uint32_t u[4]; bf16x8 v; } pf;
      pf.u[0] = csel ? B0 : A0;
      pf.u[1] = csel ? B1 : A1;
      pf.u[2] = csel ? B2 : A2;
      pf.u[3] = csel ? B3 : A3;
#pragma unroll
      for (int da = 0; da < 4; ++da) {
        int dd = da * 16 + l15;
        bf16x8 vf = *(const bf16x8*)(sV + dd * 256 +
            ((64 * ks + 16 * l4) ^ ((dd & 7) << 4) ^ (((dd >> 3) & 3) << 5)));
        oacc[da] = __builtin_amdgcn_mfma_f32_16x16x32_bf16(vf, pf.v, oacc[da], 0, 0, 0);
      }
    }
    __builtin_amdgcn_s_setprio(0);

    // ---- transition: restage K and V for t+1 ----
    asm volatile("s_waitcnt lgkmcnt(0)" ::: "memory");
    __builtin_amdgcn_sched_barrier(0);
    __builtin_amdgcn_s_barrier();        // all reads of sK/sV done
    if (t < 3) {
      stageK(t + 1);
      writeV();
      asm volatile("s_waitcnt vmcnt(0) lgkmcnt(0)" ::: "memory");
      __builtin_amdgcn_sched_barrier(0);
      __builtin_amdgcn_s_barrier();      // new tiles published
    }
  }

  // ---- epilogue: O[q][d] = oacc^T / l ----
  float rl = 1.0f / l_;
  u16* op = ctx + ((size_t)b * 512 + qt * 128 + w * 16 + l15) * 768 + h * 64;
#pragma unroll
  for (int da = 0; da < 4; ++da) {
    ushort4 o;
    o.x = f2bf(oacc[da][0] * rl);
    o.y = f2bf(oacc[da][1] * rl);
    o.z = f2bf(oacc[da][2] * rl);
    o.w = f2bf(oacc[da][3] * rl);
    *(ushort4*)(op + da * 16 + l4 * 4) = o;
  }
}

// ---------------- launch ----------------
extern "C" void kernel_launch(void* const* d_in, const int* in_sizes, int n_in,
                              void* d_out, int out_size, void* d_ws, size_t ws_size,
                              hipStream_t stream) {
  const float* x    = (const float*)d_in[0];
  const float* mask = (const float*)d_in[1];
  const float* Wq   = (const float*)d_in[2];
  const float* bq   = (const float*)d_in[3];
  const float* Wk   = (const float*)d_in[4];
  const float* bk   = (const float*)d_in[5];
  const float* Wv   = (const float*)d_in[6];
  const float* bv   = (const float*)d_in[7];
  const float* Wo   = (const float*)d_in[8];
  const float* bo   = (const float*)d_in[9];
  float* out = (float*)d_out;

  char* ws = (char*)d_ws;
  u16*   xb   = (u16*)ws;                          // 16384*768   bf16
  u16*   ctx  = (u16*)(ws + 25165824);             // 16384*768   bf16
  u16*   qkv  = (u16*)(ws + 50331648);             // 16384*2304  bf16
  u16*   wtq  = (u16*)(ws + 125829120);            // 2304*768    bf16
  u16*   wto  = (u16*)(ws + 129368064);            // 768*768     bf16
  float* bqkv = (float*)(ws + 130547712);          // 2304        f32

  prep_fused_kernel<<<6720, 256, 0, stream>>>(x, xb, Wq, Wk, Wv, Wo, bq, bk, bv,
                                              wtq, wto, bqkv);
  gemm_bt_kernel<0><<<dim3(128, 18), 256, 0, stream>>>(xb, wtq, bqkv, (void*)qkv, 2304);
  attn_kernel<<<dim3(1536), dim3(512), 0, stream>>>(qkv, mask, ctx);
  gemm_bt_kernel<1><<<dim3(128, 6), 256, 0, stream>>>(ctx, wto, bo, (void*)out, 768);
}